// Round 6
// baseline (1972.163 us; speedup 1.0000x reference)
//
#include <hip/hip_runtime.h>

#define N_ASTN 200000
#define N_TESTN 10000
#define HDIM 128
#define E_AA_N 2000000
#define E_AT_N 500000
#define E_TA_N 500000
#define NBA 196  // ceil((N_ASTN+1)/1024)
#define NBT 10   // ceil((N_TESTN+1)/1024)
#define BSHIFT 7                 // 128 nodes per bucket
#define NBK_A 1563               // ceil(200000/128)
#define NBK_T 79                 // ceil(10000/128)

typedef __bf16 bf16x8 __attribute__((ext_vector_type(8)));
typedef float f32x4 __attribute__((ext_vector_type(4)));
typedef float f32x2 __attribute__((ext_vector_type(2)));

static __device__ __forceinline__ float bflo(unsigned u) {
    union { unsigned x; float f; } c; c.x = u << 16; return c.f;
}
static __device__ __forceinline__ float bfhi(unsigned u) {
    union { unsigned x; float f; } c; c.x = u & 0xffff0000u; return c.f;
}
static __device__ __forceinline__ unsigned short f2bf(float f) {
    union { float f; unsigned u; } c; c.f = f;
    unsigned u = c.u;
    return (unsigned short)((u + 0x7fffu + ((u >> 16) & 1u)) >> 16);
}
static __device__ __forceinline__ unsigned pack2(float a, float b) {
    return (unsigned)f2bf(a) | ((unsigned)f2bf(b) << 16);
}
// unpack a bf16 pair into {lo, hi} fp32 vector; f32x2 accumulate lets the
// backend select v_pk_add_f32. (Proven path.)
static __device__ __forceinline__ f32x2 unpk(unsigned u) {
    union { unsigned q[2]; f32x2 v; } t;
    t.q[0] = u << 16;
    t.q[1] = u & 0xffff0000u;
    return t.v;
}

#define ACC4(S, U) \
    S[0] += unpk((U).x); S[1] += unpk((U).y); \
    S[2] += unpk((U).z); S[3] += unpk((U).w);

// ---------------- dtype detection ----------------

__global__ void detect_k(const unsigned short* __restrict__ p, int* __restrict__ flag) {
    __shared__ int cnt;
    if (threadIdx.x == 0) cnt = 0;
    __syncthreads();
    int local = 0;
    for (int i = threadIdx.x; i < 8192; i += 256) {
        unsigned e = ((unsigned)p[i] >> 7) & 0xFFu;
        if (e >= 158u) local++;
    }
    atomicAdd(&cnt, local);
    __syncthreads();
    if (threadIdx.x == 0) *flag = (cnt > 64) ? 1 : 0;
}

// ---------------- param conversion ----------------

struct ConvSpec {
    const void* src[11];
    int off[11];
    int total;
};

__global__ void conv_params_k(ConvSpec spec, const int* __restrict__ flag,
                              unsigned short* __restrict__ dst) {
    int f32 = *flag;
    int i = blockIdx.x * blockDim.x + threadIdx.x;
    int stride = gridDim.x * blockDim.x;
    for (; i < spec.total; i += stride) {
        int s = 10;
        for (int k = 1; k < 11; k++) {
            if (i < spec.off[k]) { s = k - 1; break; }
        }
        int j = i - spec.off[s];
        unsigned short v;
        if (f32) v = f2bf(((const float*)spec.src[s])[j]);
        else     v = ((const unsigned short*)spec.src[s])[j];
        dst[i] = v;
    }
}

// ---------------- CSR build (fused 3-type kernels) ----------------

__global__ void count3_k(const int* __restrict__ dAA, const int* __restrict__ dTA,
                         const int* __restrict__ dAT,
                         int* __restrict__ cAA, int* __restrict__ cTA, int* __restrict__ cAT) {
    int i = blockIdx.x * blockDim.x + threadIdx.x;
    int stride = gridDim.x * blockDim.x;
    const int T = E_AA_N + E_TA_N + E_AT_N;
    for (; i < T; i += stride) {
        if (i < E_AA_N) {
            unsigned d = (unsigned)dAA[i];
            if (d < (unsigned)N_ASTN) atomicAdd(&cAA[d], 1);
        } else if (i < E_AA_N + E_TA_N) {
            unsigned d = (unsigned)dTA[i - E_AA_N];
            if (d < (unsigned)N_ASTN) atomicAdd(&cTA[d], 1);
        } else {
            unsigned d = (unsigned)dAT[i - (E_AA_N + E_TA_N)];
            if (d < (unsigned)N_TESTN) atomicAdd(&cAT[d], 1);
        }
    }
}

__global__ void scan_bsum3(const int* __restrict__ cA, const int* __restrict__ cT,
                           const int* __restrict__ cX,
                           int* __restrict__ bA, int* __restrict__ bT, int* __restrict__ bX) {
    __shared__ int lds[256];
    int b = blockIdx.x, tid = threadIdx.x;
    const int* in; int n; int* bsum; int bb;
    if (b < NBA)            { in = cA; n = N_ASTN + 1;  bsum = bA; bb = b; }
    else if (b < 2 * NBA)   { in = cT; n = N_ASTN + 1;  bsum = bT; bb = b - NBA; }
    else                    { in = cX; n = N_TESTN + 1; bsum = bX; bb = b - 2 * NBA; }
    int base = bb * 1024 + tid * 4;
    int s = 0;
#pragma unroll
    for (int j = 0; j < 4; j++) { int i = base + j; if (i < n) s += in[i]; }
    lds[tid] = s; __syncthreads();
    for (int off = 128; off; off >>= 1) {
        if (tid < off) lds[tid] += lds[tid + off];
        __syncthreads();
    }
    if (tid == 0) bsum[bb] = lds[0];
}

__global__ void scan_top3(int* __restrict__ bA, int* __restrict__ bT, int* __restrict__ bX) {
    __shared__ int lds[256];
    int b = blockIdx.x, tid = threadIdx.x;
    int* bsum; int nb;
    if (b == 0)      { bsum = bA; nb = NBA; }
    else if (b == 1) { bsum = bT; nb = NBA; }
    else             { bsum = bX; nb = NBT; }
    int v = (tid < nb) ? bsum[tid] : 0;
    lds[tid] = v; __syncthreads();
    for (int off = 1; off < 256; off <<= 1) {
        int t = (tid >= off) ? lds[tid - off] : 0;
        __syncthreads();
        lds[tid] += t;
        __syncthreads();
    }
    if (tid < nb) bsum[tid] = lds[tid] - v;  // exclusive
}

__global__ void scan_final3(const int* __restrict__ cA, const int* __restrict__ cT,
                            const int* __restrict__ cX,
                            const int* __restrict__ bA, const int* __restrict__ bT,
                            const int* __restrict__ bX,
                            int* __restrict__ ipA, int* __restrict__ ipT, int* __restrict__ ipX) {
    __shared__ int lds[256];
    int b = blockIdx.x, tid = threadIdx.x;
    const int* in; int n; const int* bsum; int* out; int bb;
    if (b < NBA)          { in = cA; n = N_ASTN + 1;  bsum = bA; out = ipA; bb = b; }
    else if (b < 2 * NBA) { in = cT; n = N_ASTN + 1;  bsum = bT; out = ipT; bb = b - NBA; }
    else                  { in = cX; n = N_TESTN + 1; bsum = bX; out = ipX; bb = b - 2 * NBA; }
    int base = bb * 1024 + tid * 4;
    int v[4]; int s = 0;
#pragma unroll
    for (int j = 0; j < 4; j++) { int i = base + j; v[j] = (i < n) ? in[i] : 0; s += v[j]; }
    lds[tid] = s; __syncthreads();
    for (int off = 1; off < 256; off <<= 1) {
        int t = (tid >= off) ? lds[tid - off] : 0;
        __syncthreads();
        lds[tid] += t;
        __syncthreads();
    }
    int texcl = lds[tid] - s;
    int run = bsum[bb] + texcl;
#pragma unroll
    for (int j = 0; j < 4; j++) { int i = base + j; if (i < n) out[i] = run; run += v[j]; }
}

// ---- pass A: scatter edges into dst-bucket regions (bucket = dst>>7).
// Bucket start = ip[b<<7] (free from the node-level scan). The active write
// frontier is ~NBK lines -> L2-resident -> no write amplification.

__global__ void bucket3_k(
    const int* __restrict__ sAA, const int* __restrict__ dAA,
    const int* __restrict__ ipAA, int* __restrict__ bcAA, uint2* __restrict__ prAA,
    const int* __restrict__ sTA, const int* __restrict__ dTA,
    const int* __restrict__ ipTA, int* __restrict__ bcTA, uint2* __restrict__ prTA,
    const int* __restrict__ sAT, const int* __restrict__ dAT,
    const int* __restrict__ ipAT, int* __restrict__ bcAT, uint2* __restrict__ prAT)
{
    int i = blockIdx.x * blockDim.x + threadIdx.x;
    int stride = gridDim.x * blockDim.x;
    const int T = E_AA_N + E_TA_N + E_AT_N;
    for (; i < T; i += stride) {
        const int *src, *dst, *ip; int* bc; uint2* pr; int nN, nE, j;
        if (i < E_AA_N) {
            j = i; src = sAA; dst = dAA; ip = ipAA; bc = bcAA; pr = prAA;
            nN = N_ASTN; nE = E_AA_N;
        } else if (i < E_AA_N + E_TA_N) {
            j = i - E_AA_N; src = sTA; dst = dTA; ip = ipTA; bc = bcTA; pr = prTA;
            nN = N_ASTN; nE = E_TA_N;
        } else {
            j = i - (E_AA_N + E_TA_N); src = sAT; dst = dAT; ip = ipAT; bc = bcAT; pr = prAT;
            nN = N_TESTN; nE = E_AT_N;
        }
        unsigned d = (unsigned)dst[j];
        if (d >= (unsigned)nN) continue;
        int b = (int)(d >> BSHIFT);
        unsigned pos = (unsigned)(ip[b << BSHIFT] + atomicAdd(&bc[b], 1));
        if (pos < (unsigned)nE) {
            uint2 p; p.x = (unsigned)src[j]; p.y = d;
            pr[pos] = p;
        }
    }
}

// ---- pass B: stream bucket-sorted pairs (coalesced read); fine writes land
// inside a ~5KB window per bucket -> L2-resident -> no write amplification.

__global__ void fillfine3_k(
    const uint2* __restrict__ prAA, const int* __restrict__ ipAA,
    int* __restrict__ curAA, int* __restrict__ eAA,
    const uint2* __restrict__ prTA, const int* __restrict__ ipTA,
    int* __restrict__ curTA, int* __restrict__ eTA,
    const uint2* __restrict__ prAT, const int* __restrict__ ipAT,
    int* __restrict__ curAT, int* __restrict__ eAT)
{
    int totAA = ipAA[N_ASTN];
    int totTA = ipTA[N_ASTN];
    int totAT = ipAT[N_TESTN];
    int i = blockIdx.x * blockDim.x + threadIdx.x;
    int stride = gridDim.x * blockDim.x;
    const int T = E_AA_N + E_TA_N + E_AT_N;
    for (; i < T; i += stride) {
        const uint2* pr; const int* ip; int* cur; int* ed; int nE, j, tot;
        if (i < E_AA_N) {
            j = i; pr = prAA; ip = ipAA; cur = curAA; ed = eAA; nE = E_AA_N; tot = totAA;
        } else if (i < E_AA_N + E_TA_N) {
            j = i - E_AA_N; pr = prTA; ip = ipTA; cur = curTA; ed = eTA; nE = E_TA_N; tot = totTA;
        } else {
            j = i - (E_AA_N + E_TA_N); pr = prAT; ip = ipAT; cur = curAT; ed = eAT; nE = E_AT_N; tot = totAT;
        }
        if (j >= tot) continue;
        uint2 p = pr[j];
        unsigned d = p.y;
        unsigned pos = (unsigned)(ip[d] + atomicAdd(&cur[d], 1));
        if (pos < (unsigned)nE) ed[pos] = (int)p.x;
    }
}

// ---------------- encoder ----------------

__global__ void encode_emb(const int* __restrict__ label, const unsigned* __restrict__ embU,
                           unsigned* __restrict__ hAU) {
    int idx = blockIdx.x * blockDim.x + threadIdx.x;  // over N_AST*32
    int node = idx >> 5, c = idx & 31;
    int lb = label[node] & 127;
    hAU[node * 64 + c] = embU[lb * 32 + c];
}

__global__ void init_test(const unsigned* __restrict__ tEmbU, unsigned* __restrict__ hTU) {
    int idx = blockIdx.x * blockDim.x + threadIdx.x;  // over N_TESTN*64
    int node = idx >> 6, c = idx & 63;
    hTU[node * 64 + c] = tEmbU[c];
}

// ---------------- GEMM: C[M,N] = A[M,K] @ W[K,N] (+bias), fp32 acc -----
// Row-block form: each wave owns a full 16xN output block; ONE A-load per
// 32-wide K-step feeds NST MFMAs (acc[NST] static-indexed, no scratch).

template<int NST>
__global__ void __launch_bounds__(256) gemm_rowblk(
    const void* __restrict__ Araw, const __bf16* __restrict__ W,
    const __bf16* __restrict__ bias, __bf16* __restrict__ C,
    int M, int K, int lda, int ldc, const int* __restrict__ flagp)
{
    __shared__ __bf16 sW[16384];
    int a_f32 = flagp ? *flagp : 0;
    int tid = threadIdx.x;
    int nkb = K >> 5;
    const int N = NST * 16;
    int ngroups = nkb * NST * 64;
    for (int g = tid; g < ngroups; g += 256) {
        int l = g & 63;
        int sk = g >> 6;
        int s = sk % NST, kb = sk / NST;
        int krow = kb * 32 + ((l >> 4) << 3);
        int col = s * 16 + (l & 15);
        bf16x8 tmp;
#pragma unroll
        for (int j = 0; j < 8; j++) tmp[j] = W[(krow + j) * N + col];
        *(bf16x8*)(&sW[g * 8]) = tmp;
    }
    __syncthreads();
    int wave = tid >> 6, lane = tid & 63;
    int mrow = lane & 15, koff = (lane >> 4) << 3;
    int tilesM = M >> 4;
    for (int mt = blockIdx.x * 4 + wave; mt < tilesM; mt += gridDim.x * 4) {
        int m0 = mt << 4;
        f32x4 acc[NST];
#pragma unroll
        for (int s = 0; s < NST; s++) acc[s] = (f32x4){0.f, 0.f, 0.f, 0.f};
        for (int kb = 0; kb < nkb; kb++) {
            bf16x8 a;
            if (a_f32) {
                const float* Af = (const float*)Araw + (size_t)(m0 + mrow) * lda + koff + kb * 32;
                f32x4 x0 = *(const f32x4*)Af;
                f32x4 x1 = *(const f32x4*)(Af + 4);
#pragma unroll
                for (int j = 0; j < 4; j++) { a[j] = (__bf16)x0[j]; a[4 + j] = (__bf16)x1[j]; }
            } else {
                const __bf16* Ab = (const __bf16*)Araw + (size_t)(m0 + mrow) * lda + koff + kb * 32;
                a = *(const bf16x8*)Ab;
            }
#pragma unroll
            for (int s = 0; s < NST; s++) {
                bf16x8 b = *(const bf16x8*)(&sW[((kb * NST + s) * 64 + lane) * 8]);
                acc[s] = __builtin_amdgcn_mfma_f32_16x16x32_bf16(a, b, acc[s], 0, 0, 0);
            }
        }
        int r0 = m0 + ((lane >> 4) << 2);
#pragma unroll
        for (int s = 0; s < NST; s++) {
            int col = s * 16 + (lane & 15);
            float bv = bias ? (float)bias[col] : 0.f;
#pragma unroll
            for (int i = 0; i < 4; i++)
                C[(size_t)(r0 + i) * ldc + col] = (__bf16)(acc[s][i] + bv);
        }
    }
}

// ---------------- fused test transform: hT = relu(agg @ W + b) (+res) ----

__global__ void __launch_bounds__(256) test_transform(
    const __bf16* __restrict__ A, const __bf16* __restrict__ W,
    const __bf16* __restrict__ bias, __bf16* __restrict__ C,
    int M, int resflag)
{
    __shared__ __bf16 sW[16384];
    int tid = threadIdx.x;
    for (int g = tid; g < 2048; g += 256) {
        int l = g & 63;
        int sk = g >> 6;
        int s = sk & 7, kb = sk >> 3;
        int krow = kb * 32 + ((l >> 4) << 3);
        int col = s * 16 + (l & 15);
        bf16x8 tmp;
#pragma unroll
        for (int j = 0; j < 8; j++) tmp[j] = W[(krow + j) * 128 + col];
        *(bf16x8*)(&sW[g * 8]) = tmp;
    }
    __syncthreads();
    int wave = tid >> 6, lane = tid & 63;
    int mrow = lane & 15, koff = (lane >> 4) << 3;
    int total = (M >> 4) * 8;
    for (int t = blockIdx.x * 4 + wave; t < total; t += gridDim.x * 4) {
        int s = t & 7;
        int m0 = (t >> 3) << 4;
        f32x4 acc = {0.f, 0.f, 0.f, 0.f};
#pragma unroll
        for (int kb = 0; kb < 4; kb++) {
            bf16x8 a = *(const bf16x8*)(A + (size_t)(m0 + mrow) * 128 + koff + kb * 32);
            bf16x8 b = *(const bf16x8*)(&sW[((kb * 8 + s) * 64 + lane) * 8]);
            acc = __builtin_amdgcn_mfma_f32_16x16x32_bf16(a, b, acc, 0, 0, 0);
        }
        int col = s * 16 + (lane & 15);
        float bv = (float)bias[col];
        int r0 = m0 + ((lane >> 4) << 2);
#pragma unroll
        for (int i = 0; i < 4; i++) {
            float v = fmaxf(acc[i] + bv, 0.f);
            if (resflag) v += (float)C[(size_t)(r0 + i) * 128 + col];
            C[(size_t)(r0 + i) * 128 + col] = (__bf16)v;
        }
    }
}

// ---------------- aggregation: ONE 16-lane group per node, 4 nodes/wave ----
// aa loop unrolled x4 for MLP. DECODE=1 fuses the decoder (layer 4):
// logits/softmax written directly, hA write skipped.

template<int DECODE>
__global__ void __launch_bounds__(256) ast_update(
    const uint4* __restrict__ TAq, const uint4* __restrict__ TTq,
    const int* __restrict__ ipA, const int* __restrict__ eA,
    const int* __restrict__ ipT, const int* __restrict__ eT,
    const uint4* __restrict__ biasq, unsigned* __restrict__ h,
    int n, int resflag,
    const uint4* __restrict__ decWq, const unsigned* __restrict__ decbU,
    void* __restrict__ outp, const int* __restrict__ flagp)
{
    int node = (blockIdx.x * blockDim.x + threadIdx.x) >> 4;
    int l = threadIdx.x & 15;
    if (node >= n) return;
    const char* TAb = (const char*)TAq;
    const char* TTb = (const char*)TTq;
    unsigned loff = (unsigned)l << 4;

    int a0 = ipA[node], a1 = ipA[node + 1];
    int t0 = ipT[node], t1 = ipT[node + 1];

    f32x2 sa[4] = {{0.f,0.f},{0.f,0.f},{0.f,0.f},{0.f,0.f}};
    {
        int e = a0;
        for (; e + 3 < a1; e += 4) {
            unsigned o0 = ((unsigned)eA[e]     << 8) + loff;
            unsigned o1 = ((unsigned)eA[e + 1] << 8) + loff;
            unsigned o2 = ((unsigned)eA[e + 2] << 8) + loff;
            unsigned o3 = ((unsigned)eA[e + 3] << 8) + loff;
            uint4 u0 = *(const uint4*)(TAb + o0);
            uint4 u1 = *(const uint4*)(TAb + o1);
            uint4 u2 = *(const uint4*)(TAb + o2);
            uint4 u3 = *(const uint4*)(TAb + o3);
            ACC4(sa, u0) ACC4(sa, u1) ACC4(sa, u2) ACC4(sa, u3)
        }
        for (; e < a1; e++) {
            unsigned o0 = ((unsigned)eA[e] << 8) + loff;
            uint4 u0 = *(const uint4*)(TAb + o0);
            ACC4(sa, u0)
        }
    }
    f32x2 st[4] = {{0.f,0.f},{0.f,0.f},{0.f,0.f},{0.f,0.f}};
    {
        int e = t0;
        for (; e + 1 < t1; e += 2) {
            unsigned o0 = ((unsigned)eT[e]     << 8) + loff;
            unsigned o1 = ((unsigned)eT[e + 1] << 8) + loff;
            uint4 u0 = *(const uint4*)(TTb + o0);
            uint4 u1 = *(const uint4*)(TTb + o1);
            ACC4(st, u0) ACC4(st, u1)
        }
        if (e < t1) {
            unsigned o0 = ((unsigned)eT[e] << 8) + loff;
            uint4 u0 = *(const uint4*)(TTb + o0);
            ACC4(st, u0)
        }
    }
    int da = a1 - a0; if (da < 1) da = 1;
    int dt = t1 - t0; if (dt < 1) dt = 1;
    float inva = 1.0f / (float)da, invt = 1.0f / (float)dt;
    uint4 ub = biasq[l];
    float v[8];
    v[0] = sa[0].x * inva + st[0].x * invt + bflo(ub.x);
    v[1] = sa[0].y * inva + st[0].y * invt + bfhi(ub.x);
    v[2] = sa[1].x * inva + st[1].x * invt + bflo(ub.y);
    v[3] = sa[1].y * inva + st[1].y * invt + bfhi(ub.y);
    v[4] = sa[2].x * inva + st[2].x * invt + bflo(ub.z);
    v[5] = sa[2].y * inva + st[2].y * invt + bfhi(ub.z);
    v[6] = sa[3].x * inva + st[3].x * invt + bflo(ub.w);
    v[7] = sa[3].y * inva + st[3].y * invt + bfhi(ub.w);
#pragma unroll
    for (int j = 0; j < 8; j++) v[j] = fmaxf(v[j], 0.f);

    if (DECODE) {
        // logits = relu(h) . dec_W + dec_b ; lane l holds features 8l..8l+7
        uint4 w0 = decWq[l * 2], w1 = decWq[l * 2 + 1];
        float p0 = 0.f, p1 = 0.f;
        p0 += v[0] * bflo(w0.x); p1 += v[0] * bfhi(w0.x);
        p0 += v[1] * bflo(w0.y); p1 += v[1] * bfhi(w0.y);
        p0 += v[2] * bflo(w0.z); p1 += v[2] * bfhi(w0.z);
        p0 += v[3] * bflo(w0.w); p1 += v[3] * bfhi(w0.w);
        p0 += v[4] * bflo(w1.x); p1 += v[4] * bfhi(w1.x);
        p0 += v[5] * bflo(w1.y); p1 += v[5] * bfhi(w1.y);
        p0 += v[6] * bflo(w1.z); p1 += v[6] * bfhi(w1.z);
        p0 += v[7] * bflo(w1.w); p1 += v[7] * bfhi(w1.w);
#pragma unroll
        for (int off = 1; off < 16; off <<= 1) {
            p0 += __shfl_xor(p0, off);
            p1 += __shfl_xor(p1, off);
        }
        if (l == 0) {
            unsigned db = decbU[0];
            float l0 = p0 + bflo(db);
            float l1 = p1 + bfhi(db);
            float m = fmaxf(l0, l1);
            float e0 = __expf(l0 - m), e1 = __expf(l1 - m);
            float invs = 1.0f / (e0 + e1);
            if (*flagp) {
                float* o = (float*)outp;
                o[node * 2 + 0] = l0;
                o[node * 2 + 1] = l1;
                o[2 * N_ASTN + node * 2 + 0] = e0 * invs;
                o[2 * N_ASTN + node * 2 + 1] = e1 * invs;
            } else {
                unsigned short* o = (unsigned short*)outp;
                o[node * 2 + 0] = f2bf(l0);
                o[node * 2 + 1] = f2bf(l1);
                o[2 * N_ASTN + node * 2 + 0] = f2bf(e0 * invs);
                o[2 * N_ASTN + node * 2 + 1] = f2bf(e1 * invs);
            }
        }
        return;
    }

    uint4* hq = (uint4*)h;
    if (resflag) {
        uint4 r = hq[(size_t)node * 16 + l];
        v[0] += bflo(r.x); v[1] += bfhi(r.x);
        v[2] += bflo(r.y); v[3] += bfhi(r.y);
        v[4] += bflo(r.z); v[5] += bfhi(r.z);
        v[6] += bflo(r.w); v[7] += bfhi(r.w);
    }
    uint4 o;
    o.x = pack2(v[0], v[1]); o.y = pack2(v[2], v[3]);
    o.z = pack2(v[4], v[5]); o.w = pack2(v[6], v[7]);
    hq[(size_t)node * 16 + l] = o;
}

// mean-aggregate hA rows over at-CSR (aggregate-then-transform), x4 unroll.

__global__ void __launch_bounds__(256) agg_at_k(
    const uint4* __restrict__ Hq,
    const int* __restrict__ ip, const int* __restrict__ ed,
    uint4* __restrict__ outq, int n)
{
    int node = (blockIdx.x * blockDim.x + threadIdx.x) >> 4;
    int l = threadIdx.x & 15;
    if (node >= n) return;
    const char* Hb = (const char*)Hq;
    unsigned loff = (unsigned)l << 4;
    f32x2 sa[4] = {{0.f,0.f},{0.f,0.f},{0.f,0.f},{0.f,0.f}};
    int a0 = ip[node], a1 = ip[node + 1];
    {
        int e = a0;
        for (; e + 3 < a1; e += 4) {
            unsigned o0 = ((unsigned)ed[e]     << 8) + loff;
            unsigned o1 = ((unsigned)ed[e + 1] << 8) + loff;
            unsigned o2 = ((unsigned)ed[e + 2] << 8) + loff;
            unsigned o3 = ((unsigned)ed[e + 3] << 8) + loff;
            uint4 u0 = *(const uint4*)(Hb + o0);
            uint4 u1 = *(const uint4*)(Hb + o1);
            uint4 u2 = *(const uint4*)(Hb + o2);
            uint4 u3 = *(const uint4*)(Hb + o3);
            ACC4(sa, u0) ACC4(sa, u1) ACC4(sa, u2) ACC4(sa, u3)
        }
        for (; e < a1; e++) {
            unsigned o0 = ((unsigned)ed[e] << 8) + loff;
            uint4 u0 = *(const uint4*)(Hb + o0);
            ACC4(sa, u0)
        }
    }
    int da = a1 - a0; if (da < 1) da = 1;
    float inv = 1.0f / (float)da;
    uint4 o;
    o.x = pack2(sa[0].x * inv, sa[0].y * inv);
    o.y = pack2(sa[1].x * inv, sa[1].y * inv);
    o.z = pack2(sa[2].x * inv, sa[2].y * inv);
    o.w = pack2(sa[3].x * inv, sa[3].y * inv);
    outq[(size_t)node * 16 + l] = o;
}

// ---------------- launch ----------------

extern "C" void kernel_launch(void* const* d_in, const int* in_sizes, int n_in,
                              void* d_out, int out_size, void* d_ws, size_t ws_size,
                              hipStream_t stream) {
    const int* ast_label = (const int*)d_in[0];
    const void* ast_content = d_in[1];
    const int* src_aa = (const int*)d_in[2];
    const int* dst_aa = (const int*)d_in[3];
    const int* src_at = (const int*)d_in[4];
    const int* dst_at = (const int*)d_in[5];
    const int* src_ta = (const int*)d_in[6];
    const int* dst_ta = (const int*)d_in[7];

    char* ws = (char*)d_ws;
    size_t off = 0;
    auto alloc = [&](size_t bytes) {
        char* p = ws + off;
        off += (bytes + 255) & ~(size_t)255;
        return p;
    };
    int* flag = (int*)alloc(256);
    const int P_EMB = 0, P_CW = 8192, P_CB = 24576, P_TEMB = 24640, P_WAA = 24768,
              P_WAT = 106688, P_WTA = 188608, P_BAST = 270528, P_BTEST = 271168,
              P_DECW = 271808, P_DECB = 272064, P_TOTAL = 272066;
    __bf16* params = (__bf16*)alloc((size_t)P_TOTAL * 2);
    __bf16* hA = (__bf16*)alloc((size_t)N_ASTN * HDIM * 2);
    __bf16* TA = (__bf16*)alloc((size_t)N_ASTN * HDIM * 2);
    __bf16* hT = (__bf16*)alloc((size_t)N_TESTN * HDIM * 2);
    __bf16* TT = (__bf16*)alloc((size_t)N_TESTN * HDIM * 2);
    int* ip_aa = (int*)alloc((size_t)(N_ASTN + 1) * 4);
    int* ip_ta = (int*)alloc((size_t)(N_ASTN + 1) * 4);
    int* ip_at = (int*)alloc((size_t)(N_TESTN + 1) * 4);
    int* e_aa = (int*)alloc((size_t)E_AA_N * 4);
    int* e_ta = (int*)alloc((size_t)E_TA_N * 4);
    int* e_at = (int*)alloc((size_t)E_AT_N * 4);
    // pair buffers for the bucketed 2-pass fill
    uint2* pr_aa = (uint2*)alloc((size_t)E_AA_N * 8);
    uint2* pr_ta = (uint2*)alloc((size_t)E_TA_N * 8);
    uint2* pr_at = (uint2*)alloc((size_t)E_AT_N * 8);
    char* zbase = alloc(((size_t)(N_ASTN + 1 + N_ASTN) * 2 + (N_TESTN + 1 + N_TESTN)
                         + NBK_A * 2 + NBK_T) * 4);
    int* cnt_aa = (int*)zbase;
    int* cur_aa = cnt_aa + (N_ASTN + 1);
    int* cnt_ta = cur_aa + N_ASTN;
    int* cur_ta = cnt_ta + (N_ASTN + 1);
    int* cnt_at = cur_ta + N_ASTN;
    int* cur_at = cnt_at + (N_TESTN + 1);
    int* bc_aa = cur_at + N_TESTN;
    int* bc_ta = bc_aa + NBK_A;
    int* bc_at = bc_ta + NBK_A;
    size_t zbytes = ((size_t)(N_ASTN + 1 + N_ASTN) * 2 + (N_TESTN + 1 + N_TESTN)
                     + NBK_A * 2 + NBK_T) * 4;
    int* bsumA = (int*)alloc(256 * 4);
    int* bsumT = (int*)alloc(256 * 4);
    int* bsumX = (int*)alloc(256 * 4);
    // aggAT (10000x128 bf16 = 2.56 MB) overlays the CSR scratch (cnt/cur,
    // ~3.2 MB) which is dead after fillfine3_k.
    __bf16* aggAT = (__bf16*)zbase;

    if (ws_size < off) {
        hipMemsetAsync(d_out, 0, (size_t)out_size * 2, stream);
        return;
    }

    detect_k<<<1, 256, 0, stream>>>((const unsigned short*)ast_content, flag);
    ConvSpec spec;
    spec.src[0] = d_in[9];  spec.off[0] = P_EMB;
    spec.src[1] = d_in[10]; spec.off[1] = P_CW;
    spec.src[2] = d_in[11]; spec.off[2] = P_CB;
    spec.src[3] = d_in[12]; spec.off[3] = P_TEMB;
    spec.src[4] = d_in[13]; spec.off[4] = P_WAA;
    spec.src[5] = d_in[14]; spec.off[5] = P_WAT;
    spec.src[6] = d_in[15]; spec.off[6] = P_WTA;
    spec.src[7] = d_in[16]; spec.off[7] = P_BAST;
    spec.src[8] = d_in[17]; spec.off[8] = P_BTEST;
    spec.src[9] = d_in[18]; spec.off[9] = P_DECW;
    spec.src[10] = d_in[19]; spec.off[10] = P_DECB;
    spec.total = P_TOTAL;
    conv_params_k<<<256, 256, 0, stream>>>(spec, flag, (unsigned short*)params);

    hipMemsetAsync(zbase, 0, zbytes, stream);

    count3_k<<<3072, 256, 0, stream>>>(dst_aa, dst_ta, dst_at, cnt_aa, cnt_ta, cnt_at);
    scan_bsum3<<<2 * NBA + NBT, 256, 0, stream>>>(cnt_aa, cnt_ta, cnt_at, bsumA, bsumT, bsumX);
    scan_top3<<<3, 256, 0, stream>>>(bsumA, bsumT, bsumX);
    scan_final3<<<2 * NBA + NBT, 256, 0, stream>>>(cnt_aa, cnt_ta, cnt_at,
                                                   bsumA, bsumT, bsumX,
                                                   ip_aa, ip_ta, ip_at);
    bucket3_k<<<3072, 256, 0, stream>>>(src_aa, dst_aa, ip_aa, bc_aa, pr_aa,
                                        src_ta, dst_ta, ip_ta, bc_ta, pr_ta,
                                        src_at, dst_at, ip_at, bc_at, pr_at);
    fillfine3_k<<<3072, 256, 0, stream>>>(pr_aa, ip_aa, cur_aa, e_aa,
                                          pr_ta, ip_ta, cur_ta, e_ta,
                                          pr_at, ip_at, cur_at, e_at);

    encode_emb<<<N_ASTN * 32 / 256, 256, 0, stream>>>(ast_label, (const unsigned*)(params + P_EMB),
                                                      (unsigned*)hA);
    gemm_rowblk<4><<<1568, 256, 0, stream>>>(ast_content, params + P_CW, params + P_CB,
                                             hA + 64, N_ASTN, 256, 256, HDIM, flag);
    init_test<<<N_TESTN * 64 / 256, 256, 0, stream>>>((const unsigned*)(params + P_TEMB),
                                                      (unsigned*)hT);

    const uint4* decWq = (const uint4*)(params + P_DECW);
    const unsigned* decbU = (const unsigned*)(params + P_DECB);
    const int resflags[5] = {0, 1, 0, 1, 0};
    for (int l = 0; l < 5; l++) {
        const __bf16* Waa = params + P_WAA + (size_t)l * HDIM * HDIM;
        const __bf16* Wat = params + P_WAT + (size_t)l * HDIM * HDIM;
        const __bf16* Wta = params + P_WTA + (size_t)l * HDIM * HDIM;
        // TT = old hT @ Wta (must precede hT update)
        gemm_rowblk<8><<<160, 256, 0, stream>>>(hT, Wta, nullptr, TT, N_TESTN, HDIM, HDIM, HDIM, nullptr);
        // aggregate-then-transform for at-edges: mean(hA[src]) then tiny GEMM
        agg_at_k<<<N_TESTN / 16, 256, 0, stream>>>(
            (const uint4*)hA, ip_at, e_at, (uint4*)aggAT, N_TESTN);
        gemm_rowblk<8><<<1568, 256, 0, stream>>>(hA, Waa, nullptr, TA, N_ASTN, HDIM, HDIM, HDIM, nullptr);
        test_transform<<<256, 256, 0, stream>>>(
            aggAT, Wat, params + P_BTEST + (size_t)l * HDIM, hT, N_TESTN, resflags[l]);
        if (l < 4) {
            ast_update<0><<<N_ASTN / 16, 256, 0, stream>>>(
                (const uint4*)TA, (const uint4*)TT, ip_aa, e_aa, ip_ta, e_ta,
                (const uint4*)(params + P_BAST + (size_t)l * HDIM), (unsigned*)hA,
                N_ASTN, resflags[l], nullptr, nullptr, nullptr, nullptr);
        } else {
            // layer 4: fused decoder epilogue, hA write skipped
            ast_update<1><<<N_ASTN / 16, 256, 0, stream>>>(
                (const uint4*)TA, (const uint4*)TT, ip_aa, e_aa, ip_ta, e_ta,
                (const uint4*)(params + P_BAST + (size_t)l * HDIM), (unsigned*)hA,
                N_ASTN, 0, decWq, decbU, d_out, flag);
        }
    }
}

// Round 7
// 1420.516 us; speedup vs baseline: 1.3883x; 1.3883x over previous
//
#include <hip/hip_runtime.h>

#define N_ASTN 200000
#define N_TESTN 10000
#define HDIM 128
#define E_AA_N 2000000
#define E_AT_N 500000
#define E_TA_N 500000
#define NBA 196  // ceil((N_ASTN+1)/1024)
#define NBT 10   // ceil((N_TESTN+1)/1024)

typedef __bf16 bf16x8 __attribute__((ext_vector_type(8)));
typedef float f32x4 __attribute__((ext_vector_type(4)));
typedef float f32x2 __attribute__((ext_vector_type(2)));

static __device__ __forceinline__ float bflo(unsigned u) {
    union { unsigned x; float f; } c; c.x = u << 16; return c.f;
}
static __device__ __forceinline__ float bfhi(unsigned u) {
    union { unsigned x; float f; } c; c.x = u & 0xffff0000u; return c.f;
}
static __device__ __forceinline__ unsigned short f2bf(float f) {
    union { float f; unsigned u; } c; c.f = f;
    unsigned u = c.u;
    return (unsigned short)((u + 0x7fffu + ((u >> 16) & 1u)) >> 16);
}
static __device__ __forceinline__ unsigned pack2(float a, float b) {
    return (unsigned)f2bf(a) | ((unsigned)f2bf(b) << 16);
}
// unpack a bf16 pair into {lo, hi} fp32 vector; f32x2 accumulate lets the
// backend select v_pk_add_f32. (Proven path.)
static __device__ __forceinline__ f32x2 unpk(unsigned u) {
    union { unsigned q[2]; f32x2 v; } t;
    t.q[0] = u << 16;
    t.q[1] = u & 0xffff0000u;
    return t.v;
}

#define ACC4(S, U) \
    S[0] += unpk((U).x); S[1] += unpk((U).y); \
    S[2] += unpk((U).z); S[3] += unpk((U).w);

// ---------------- dtype detection ----------------

__global__ void detect_k(const unsigned short* __restrict__ p, int* __restrict__ flag) {
    __shared__ int cnt;
    if (threadIdx.x == 0) cnt = 0;
    __syncthreads();
    int local = 0;
    for (int i = threadIdx.x; i < 8192; i += 256) {
        unsigned e = ((unsigned)p[i] >> 7) & 0xFFu;
        if (e >= 158u) local++;
    }
    atomicAdd(&cnt, local);
    __syncthreads();
    if (threadIdx.x == 0) *flag = (cnt > 64) ? 1 : 0;
}

// ---------------- param conversion ----------------

struct ConvSpec {
    const void* src[11];
    int off[11];
    int total;
};

__global__ void conv_params_k(ConvSpec spec, const int* __restrict__ flag,
                              unsigned short* __restrict__ dst) {
    int f32 = *flag;
    int i = blockIdx.x * blockDim.x + threadIdx.x;
    int stride = gridDim.x * blockDim.x;
    for (; i < spec.total; i += stride) {
        int s = 10;
        for (int k = 1; k < 11; k++) {
            if (i < spec.off[k]) { s = k - 1; break; }
        }
        int j = i - spec.off[s];
        unsigned short v;
        if (f32) v = f2bf(((const float*)spec.src[s])[j]);
        else     v = ((const unsigned short*)spec.src[s])[j];
        dst[i] = v;
    }
}

// ---------------- CSR build (fused 3-type kernels) ----------------
// count3_k persists each edge's rank (atomicAdd return) so the fill pass
// needs NO atomics: pos = ip[dst] + rank.

__global__ void count3_k(const int* __restrict__ dAA, const int* __restrict__ dTA,
                         const int* __restrict__ dAT,
                         int* __restrict__ cAA, int* __restrict__ cTA, int* __restrict__ cAT,
                         int* __restrict__ rAA, int* __restrict__ rTA, int* __restrict__ rAT) {
    int i = blockIdx.x * blockDim.x + threadIdx.x;
    int stride = gridDim.x * blockDim.x;
    const int T = E_AA_N + E_TA_N + E_AT_N;
    for (; i < T; i += stride) {
        if (i < E_AA_N) {
            unsigned d = (unsigned)dAA[i];
            if (d < (unsigned)N_ASTN) rAA[i] = atomicAdd(&cAA[d], 1);
        } else if (i < E_AA_N + E_TA_N) {
            int j = i - E_AA_N;
            unsigned d = (unsigned)dTA[j];
            if (d < (unsigned)N_ASTN) rTA[j] = atomicAdd(&cTA[d], 1);
        } else {
            int j = i - (E_AA_N + E_TA_N);
            unsigned d = (unsigned)dAT[j];
            if (d < (unsigned)N_TESTN) rAT[j] = atomicAdd(&cAT[d], 1);
        }
    }
}

__global__ void scan_bsum3(const int* __restrict__ cA, const int* __restrict__ cT,
                           const int* __restrict__ cX,
                           int* __restrict__ bA, int* __restrict__ bT, int* __restrict__ bX) {
    __shared__ int lds[256];
    int b = blockIdx.x, tid = threadIdx.x;
    const int* in; int n; int* bsum; int bb;
    if (b < NBA)            { in = cA; n = N_ASTN + 1;  bsum = bA; bb = b; }
    else if (b < 2 * NBA)   { in = cT; n = N_ASTN + 1;  bsum = bT; bb = b - NBA; }
    else                    { in = cX; n = N_TESTN + 1; bsum = bX; bb = b - 2 * NBA; }
    int base = bb * 1024 + tid * 4;
    int s = 0;
#pragma unroll
    for (int j = 0; j < 4; j++) { int i = base + j; if (i < n) s += in[i]; }
    lds[tid] = s; __syncthreads();
    for (int off = 128; off; off >>= 1) {
        if (tid < off) lds[tid] += lds[tid + off];
        __syncthreads();
    }
    if (tid == 0) bsum[bb] = lds[0];
}

__global__ void scan_top3(int* __restrict__ bA, int* __restrict__ bT, int* __restrict__ bX) {
    __shared__ int lds[256];
    int b = blockIdx.x, tid = threadIdx.x;
    int* bsum; int nb;
    if (b == 0)      { bsum = bA; nb = NBA; }
    else if (b == 1) { bsum = bT; nb = NBA; }
    else             { bsum = bX; nb = NBT; }
    int v = (tid < nb) ? bsum[tid] : 0;
    lds[tid] = v; __syncthreads();
    for (int off = 1; off < 256; off <<= 1) {
        int t = (tid >= off) ? lds[tid - off] : 0;
        __syncthreads();
        lds[tid] += t;
        __syncthreads();
    }
    if (tid < nb) bsum[tid] = lds[tid] - v;  // exclusive
}

__global__ void scan_final3(const int* __restrict__ cA, const int* __restrict__ cT,
                            const int* __restrict__ cX,
                            const int* __restrict__ bA, const int* __restrict__ bT,
                            const int* __restrict__ bX,
                            int* __restrict__ ipA, int* __restrict__ ipT, int* __restrict__ ipX) {
    __shared__ int lds[256];
    int b = blockIdx.x, tid = threadIdx.x;
    const int* in; int n; const int* bsum; int* out; int bb;
    if (b < NBA)          { in = cA; n = N_ASTN + 1;  bsum = bA; out = ipA; bb = b; }
    else if (b < 2 * NBA) { in = cT; n = N_ASTN + 1;  bsum = bT; out = ipT; bb = b - NBA; }
    else                  { in = cX; n = N_TESTN + 1; bsum = bX; out = ipX; bb = b - 2 * NBA; }
    int base = bb * 1024 + tid * 4;
    int v[4]; int s = 0;
#pragma unroll
    for (int j = 0; j < 4; j++) { int i = base + j; v[j] = (i < n) ? in[i] : 0; s += v[j]; }
    lds[tid] = s; __syncthreads();
    for (int off = 1; off < 256; off <<= 1) {
        int t = (tid >= off) ? lds[tid - off] : 0;
        __syncthreads();
        lds[tid] += t;
        __syncthreads();
    }
    int texcl = lds[tid] - s;
    int run = bsum[bb] + texcl;
#pragma unroll
    for (int j = 0; j < 4; j++) { int i = base + j; if (i < n) out[i] = run; run += v[j]; }
}

// atomic-free fill: pos = ip[dst] + rank (rank from count3_k).

__global__ void fill3_k(const int* __restrict__ sAA, const int* __restrict__ dAA,
                        const int* __restrict__ rAA, const int* __restrict__ ipAA,
                        int* __restrict__ eAA,
                        const int* __restrict__ sTA, const int* __restrict__ dTA,
                        const int* __restrict__ rTA, const int* __restrict__ ipTA,
                        int* __restrict__ eTA,
                        const int* __restrict__ sAT, const int* __restrict__ dAT,
                        const int* __restrict__ rAT, const int* __restrict__ ipAT,
                        int* __restrict__ eAT) {
    int i = blockIdx.x * blockDim.x + threadIdx.x;
    int stride = gridDim.x * blockDim.x;
    const int T = E_AA_N + E_TA_N + E_AT_N;
    for (; i < T; i += stride) {
        const int *src, *dst, *rk, *ip; int* ed; int nN, nE, j;
        if (i < E_AA_N) {
            j = i; src = sAA; dst = dAA; rk = rAA; ip = ipAA; ed = eAA;
            nN = N_ASTN; nE = E_AA_N;
        } else if (i < E_AA_N + E_TA_N) {
            j = i - E_AA_N; src = sTA; dst = dTA; rk = rTA; ip = ipTA; ed = eTA;
            nN = N_ASTN; nE = E_TA_N;
        } else {
            j = i - (E_AA_N + E_TA_N); src = sAT; dst = dAT; rk = rAT; ip = ipAT; ed = eAT;
            nN = N_TESTN; nE = E_AT_N;
        }
        unsigned d = (unsigned)dst[j];
        if (d >= (unsigned)nN) continue;
        unsigned pos = (unsigned)(ip[d] + rk[j]);
        if (pos < (unsigned)nE) ed[pos] = src[j];
    }
}

// ---------------- encoder ----------------

__global__ void encode_emb(const int* __restrict__ label, const unsigned* __restrict__ embU,
                           unsigned* __restrict__ hAU) {
    int idx = blockIdx.x * blockDim.x + threadIdx.x;  // over N_AST*32
    int node = idx >> 5, c = idx & 31;
    int lb = label[node] & 127;
    hAU[node * 64 + c] = embU[lb * 32 + c];
}

__global__ void init_test(const unsigned* __restrict__ tEmbU, unsigned* __restrict__ hTU) {
    int idx = blockIdx.x * blockDim.x + threadIdx.x;  // over N_TESTN*64
    int node = idx >> 6, c = idx & 63;
    hTU[node * 64 + c] = tEmbU[c];
}

// ---------------- GEMM: C[M,N] = A[M,K] @ W[K,N] (+bias), fp32 acc -----
// Row-block form: each wave owns a full 16xN output block; ONE A-load per
// 32-wide K-step feeds NST MFMAs (acc[NST] static-indexed, no scratch).

template<int NST>
__global__ void __launch_bounds__(256) gemm_rowblk(
    const void* __restrict__ Araw, const __bf16* __restrict__ W,
    const __bf16* __restrict__ bias, __bf16* __restrict__ C,
    int M, int K, int lda, int ldc, const int* __restrict__ flagp)
{
    __shared__ __bf16 sW[16384];
    int a_f32 = flagp ? *flagp : 0;
    int tid = threadIdx.x;
    int nkb = K >> 5;
    const int N = NST * 16;
    int ngroups = nkb * NST * 64;
    for (int g = tid; g < ngroups; g += 256) {
        int l = g & 63;
        int sk = g >> 6;
        int s = sk % NST, kb = sk / NST;
        int krow = kb * 32 + ((l >> 4) << 3);
        int col = s * 16 + (l & 15);
        bf16x8 tmp;
#pragma unroll
        for (int j = 0; j < 8; j++) tmp[j] = W[(krow + j) * N + col];
        *(bf16x8*)(&sW[g * 8]) = tmp;
    }
    __syncthreads();
    int wave = tid >> 6, lane = tid & 63;
    int mrow = lane & 15, koff = (lane >> 4) << 3;
    int tilesM = M >> 4;
    for (int mt = blockIdx.x * 4 + wave; mt < tilesM; mt += gridDim.x * 4) {
        int m0 = mt << 4;
        f32x4 acc[NST];
#pragma unroll
        for (int s = 0; s < NST; s++) acc[s] = (f32x4){0.f, 0.f, 0.f, 0.f};
        for (int kb = 0; kb < nkb; kb++) {
            bf16x8 a;
            if (a_f32) {
                const float* Af = (const float*)Araw + (size_t)(m0 + mrow) * lda + koff + kb * 32;
                f32x4 x0 = *(const f32x4*)Af;
                f32x4 x1 = *(const f32x4*)(Af + 4);
#pragma unroll
                for (int j = 0; j < 4; j++) { a[j] = (__bf16)x0[j]; a[4 + j] = (__bf16)x1[j]; }
            } else {
                const __bf16* Ab = (const __bf16*)Araw + (size_t)(m0 + mrow) * lda + koff + kb * 32;
                a = *(const bf16x8*)Ab;
            }
#pragma unroll
            for (int s = 0; s < NST; s++) {
                bf16x8 b = *(const bf16x8*)(&sW[((kb * NST + s) * 64 + lane) * 8]);
                acc[s] = __builtin_amdgcn_mfma_f32_16x16x32_bf16(a, b, acc[s], 0, 0, 0);
            }
        }
        int r0 = m0 + ((lane >> 4) << 2);
#pragma unroll
        for (int s = 0; s < NST; s++) {
            int col = s * 16 + (lane & 15);
            float bv = bias ? (float)bias[col] : 0.f;
#pragma unroll
            for (int i = 0; i < 4; i++)
                C[(size_t)(r0 + i) * ldc + col] = (__bf16)(acc[s][i] + bv);
        }
    }
}

// ---------------- fused test transform: hT = relu(agg @ W + b) (+res) ----

__global__ void __launch_bounds__(256) test_transform(
    const __bf16* __restrict__ A, const __bf16* __restrict__ W,
    const __bf16* __restrict__ bias, __bf16* __restrict__ C,
    int M, int resflag)
{
    __shared__ __bf16 sW[16384];
    int tid = threadIdx.x;
    for (int g = tid; g < 2048; g += 256) {
        int l = g & 63;
        int sk = g >> 6;
        int s = sk & 7, kb = sk >> 3;
        int krow = kb * 32 + ((l >> 4) << 3);
        int col = s * 16 + (l & 15);
        bf16x8 tmp;
#pragma unroll
        for (int j = 0; j < 8; j++) tmp[j] = W[(krow + j) * 128 + col];
        *(bf16x8*)(&sW[g * 8]) = tmp;
    }
    __syncthreads();
    int wave = tid >> 6, lane = tid & 63;
    int mrow = lane & 15, koff = (lane >> 4) << 3;
    int total = (M >> 4) * 8;
    for (int t = blockIdx.x * 4 + wave; t < total; t += gridDim.x * 4) {
        int s = t & 7;
        int m0 = (t >> 3) << 4;
        f32x4 acc = {0.f, 0.f, 0.f, 0.f};
#pragma unroll
        for (int kb = 0; kb < 4; kb++) {
            bf16x8 a = *(const bf16x8*)(A + (size_t)(m0 + mrow) * 128 + koff + kb * 32);
            bf16x8 b = *(const bf16x8*)(&sW[((kb * 8 + s) * 64 + lane) * 8]);
            acc = __builtin_amdgcn_mfma_f32_16x16x32_bf16(a, b, acc, 0, 0, 0);
        }
        int col = s * 16 + (lane & 15);
        float bv = (float)bias[col];
        int r0 = m0 + ((lane >> 4) << 2);
#pragma unroll
        for (int i = 0; i < 4; i++) {
            float v = fmaxf(acc[i] + bv, 0.f);
            if (resflag) v += (float)C[(size_t)(r0 + i) * 128 + col];
            C[(size_t)(r0 + i) * 128 + col] = (__bf16)v;
        }
    }
}

// ---------------- aggregation: ONE 16-lane group per node, 4 nodes/wave ----
// aa loop unrolled x4 for MLP. DECODE=1 fuses the decoder (layer 4):
// logits/softmax written directly, hA write skipped.

template<int DECODE>
__global__ void __launch_bounds__(256) ast_update(
    const uint4* __restrict__ TAq, const uint4* __restrict__ TTq,
    const int* __restrict__ ipA, const int* __restrict__ eA,
    const int* __restrict__ ipT, const int* __restrict__ eT,
    const uint4* __restrict__ biasq, unsigned* __restrict__ h,
    int n, int resflag,
    const uint4* __restrict__ decWq, const unsigned* __restrict__ decbU,
    void* __restrict__ outp, const int* __restrict__ flagp)
{
    int node = (blockIdx.x * blockDim.x + threadIdx.x) >> 4;
    int l = threadIdx.x & 15;
    if (node >= n) return;
    const char* TAb = (const char*)TAq;
    const char* TTb = (const char*)TTq;
    unsigned loff = (unsigned)l << 4;

    int a0 = ipA[node], a1 = ipA[node + 1];
    int t0 = ipT[node], t1 = ipT[node + 1];

    f32x2 sa[4] = {{0.f,0.f},{0.f,0.f},{0.f,0.f},{0.f,0.f}};
    {
        int e = a0;
        for (; e + 3 < a1; e += 4) {
            unsigned o0 = ((unsigned)eA[e]     << 8) + loff;
            unsigned o1 = ((unsigned)eA[e + 1] << 8) + loff;
            unsigned o2 = ((unsigned)eA[e + 2] << 8) + loff;
            unsigned o3 = ((unsigned)eA[e + 3] << 8) + loff;
            uint4 u0 = *(const uint4*)(TAb + o0);
            uint4 u1 = *(const uint4*)(TAb + o1);
            uint4 u2 = *(const uint4*)(TAb + o2);
            uint4 u3 = *(const uint4*)(TAb + o3);
            ACC4(sa, u0) ACC4(sa, u1) ACC4(sa, u2) ACC4(sa, u3)
        }
        for (; e < a1; e++) {
            unsigned o0 = ((unsigned)eA[e] << 8) + loff;
            uint4 u0 = *(const uint4*)(TAb + o0);
            ACC4(sa, u0)
        }
    }
    f32x2 st[4] = {{0.f,0.f},{0.f,0.f},{0.f,0.f},{0.f,0.f}};
    {
        int e = t0;
        for (; e + 1 < t1; e += 2) {
            unsigned o0 = ((unsigned)eT[e]     << 8) + loff;
            unsigned o1 = ((unsigned)eT[e + 1] << 8) + loff;
            uint4 u0 = *(const uint4*)(TTb + o0);
            uint4 u1 = *(const uint4*)(TTb + o1);
            ACC4(st, u0) ACC4(st, u1)
        }
        if (e < t1) {
            unsigned o0 = ((unsigned)eT[e] << 8) + loff;
            uint4 u0 = *(const uint4*)(TTb + o0);
            ACC4(st, u0)
        }
    }
    int da = a1 - a0; if (da < 1) da = 1;
    int dt = t1 - t0; if (dt < 1) dt = 1;
    float inva = 1.0f / (float)da, invt = 1.0f / (float)dt;
    uint4 ub = biasq[l];
    float v[8];
    v[0] = sa[0].x * inva + st[0].x * invt + bflo(ub.x);
    v[1] = sa[0].y * inva + st[0].y * invt + bfhi(ub.x);
    v[2] = sa[1].x * inva + st[1].x * invt + bflo(ub.y);
    v[3] = sa[1].y * inva + st[1].y * invt + bfhi(ub.y);
    v[4] = sa[2].x * inva + st[2].x * invt + bflo(ub.z);
    v[5] = sa[2].y * inva + st[2].y * invt + bfhi(ub.z);
    v[6] = sa[3].x * inva + st[3].x * invt + bflo(ub.w);
    v[7] = sa[3].y * inva + st[3].y * invt + bfhi(ub.w);
#pragma unroll
    for (int j = 0; j < 8; j++) v[j] = fmaxf(v[j], 0.f);

    if (DECODE) {
        // logits = relu(h) . dec_W + dec_b ; lane l holds features 8l..8l+7
        uint4 w0 = decWq[l * 2], w1 = decWq[l * 2 + 1];
        float p0 = 0.f, p1 = 0.f;
        p0 += v[0] * bflo(w0.x); p1 += v[0] * bfhi(w0.x);
        p0 += v[1] * bflo(w0.y); p1 += v[1] * bfhi(w0.y);
        p0 += v[2] * bflo(w0.z); p1 += v[2] * bfhi(w0.z);
        p0 += v[3] * bflo(w0.w); p1 += v[3] * bfhi(w0.w);
        p0 += v[4] * bflo(w1.x); p1 += v[4] * bfhi(w1.x);
        p0 += v[5] * bflo(w1.y); p1 += v[5] * bfhi(w1.y);
        p0 += v[6] * bflo(w1.z); p1 += v[6] * bfhi(w1.z);
        p0 += v[7] * bflo(w1.w); p1 += v[7] * bfhi(w1.w);
#pragma unroll
        for (int off = 1; off < 16; off <<= 1) {
            p0 += __shfl_xor(p0, off);
            p1 += __shfl_xor(p1, off);
        }
        if (l == 0) {
            unsigned db = decbU[0];
            float l0 = p0 + bflo(db);
            float l1 = p1 + bfhi(db);
            float m = fmaxf(l0, l1);
            float e0 = __expf(l0 - m), e1 = __expf(l1 - m);
            float invs = 1.0f / (e0 + e1);
            if (*flagp) {
                float* o = (float*)outp;
                o[node * 2 + 0] = l0;
                o[node * 2 + 1] = l1;
                o[2 * N_ASTN + node * 2 + 0] = e0 * invs;
                o[2 * N_ASTN + node * 2 + 1] = e1 * invs;
            } else {
                unsigned short* o = (unsigned short*)outp;
                o[node * 2 + 0] = f2bf(l0);
                o[node * 2 + 1] = f2bf(l1);
                o[2 * N_ASTN + node * 2 + 0] = f2bf(e0 * invs);
                o[2 * N_ASTN + node * 2 + 1] = f2bf(e1 * invs);
            }
        }
        return;
    }

    uint4* hq = (uint4*)h;
    if (resflag) {
        uint4 r = hq[(size_t)node * 16 + l];
        v[0] += bflo(r.x); v[1] += bfhi(r.x);
        v[2] += bflo(r.y); v[3] += bfhi(r.y);
        v[4] += bflo(r.z); v[5] += bfhi(r.z);
        v[6] += bflo(r.w); v[7] += bfhi(r.w);
    }
    uint4 o;
    o.x = pack2(v[0], v[1]); o.y = pack2(v[2], v[3]);
    o.z = pack2(v[4], v[5]); o.w = pack2(v[6], v[7]);
    hq[(size_t)node * 16 + l] = o;
}

// mean-aggregate hA rows over at-CSR (aggregate-then-transform), x4 unroll.

__global__ void __launch_bounds__(256) agg_at_k(
    const uint4* __restrict__ Hq,
    const int* __restrict__ ip, const int* __restrict__ ed,
    uint4* __restrict__ outq, int n)
{
    int node = (blockIdx.x * blockDim.x + threadIdx.x) >> 4;
    int l = threadIdx.x & 15;
    if (node >= n) return;
    const char* Hb = (const char*)Hq;
    unsigned loff = (unsigned)l << 4;
    f32x2 sa[4] = {{0.f,0.f},{0.f,0.f},{0.f,0.f},{0.f,0.f}};
    int a0 = ip[node], a1 = ip[node + 1];
    {
        int e = a0;
        for (; e + 3 < a1; e += 4) {
            unsigned o0 = ((unsigned)ed[e]     << 8) + loff;
            unsigned o1 = ((unsigned)ed[e + 1] << 8) + loff;
            unsigned o2 = ((unsigned)ed[e + 2] << 8) + loff;
            unsigned o3 = ((unsigned)ed[e + 3] << 8) + loff;
            uint4 u0 = *(const uint4*)(Hb + o0);
            uint4 u1 = *(const uint4*)(Hb + o1);
            uint4 u2 = *(const uint4*)(Hb + o2);
            uint4 u3 = *(const uint4*)(Hb + o3);
            ACC4(sa, u0) ACC4(sa, u1) ACC4(sa, u2) ACC4(sa, u3)
        }
        for (; e < a1; e++) {
            unsigned o0 = ((unsigned)ed[e] << 8) + loff;
            uint4 u0 = *(const uint4*)(Hb + o0);
            ACC4(sa, u0)
        }
    }
    int da = a1 - a0; if (da < 1) da = 1;
    float inv = 1.0f / (float)da;
    uint4 o;
    o.x = pack2(sa[0].x * inv, sa[0].y * inv);
    o.y = pack2(sa[1].x * inv, sa[1].y * inv);
    o.z = pack2(sa[2].x * inv, sa[2].y * inv);
    o.w = pack2(sa[3].x * inv, sa[3].y * inv);
    outq[(size_t)node * 16 + l] = o;
}

// ---------------- launch ----------------

extern "C" void kernel_launch(void* const* d_in, const int* in_sizes, int n_in,
                              void* d_out, int out_size, void* d_ws, size_t ws_size,
                              hipStream_t stream) {
    const int* ast_label = (const int*)d_in[0];
    const void* ast_content = d_in[1];
    const int* src_aa = (const int*)d_in[2];
    const int* dst_aa = (const int*)d_in[3];
    const int* src_at = (const int*)d_in[4];
    const int* dst_at = (const int*)d_in[5];
    const int* src_ta = (const int*)d_in[6];
    const int* dst_ta = (const int*)d_in[7];

    char* ws = (char*)d_ws;
    size_t off = 0;
    auto alloc = [&](size_t bytes) {
        char* p = ws + off;
        off += (bytes + 255) & ~(size_t)255;
        return p;
    };
    int* flag = (int*)alloc(256);
    const int P_EMB = 0, P_CW = 8192, P_CB = 24576, P_TEMB = 24640, P_WAA = 24768,
              P_WAT = 106688, P_WTA = 188608, P_BAST = 270528, P_BTEST = 271168,
              P_DECW = 271808, P_DECB = 272064, P_TOTAL = 272066;
    __bf16* params = (__bf16*)alloc((size_t)P_TOTAL * 2);
    __bf16* hA = (__bf16*)alloc((size_t)N_ASTN * HDIM * 2);
    __bf16* TA = (__bf16*)alloc((size_t)N_ASTN * HDIM * 2);
    __bf16* hT = (__bf16*)alloc((size_t)N_TESTN * HDIM * 2);
    __bf16* TT = (__bf16*)alloc((size_t)N_TESTN * HDIM * 2);
    int* ip_aa = (int*)alloc((size_t)(N_ASTN + 1) * 4);
    int* ip_ta = (int*)alloc((size_t)(N_ASTN + 1) * 4);
    int* ip_at = (int*)alloc((size_t)(N_TESTN + 1) * 4);
    int* e_aa = (int*)alloc((size_t)E_AA_N * 4);
    int* e_ta = (int*)alloc((size_t)E_TA_N * 4);
    int* e_at = (int*)alloc((size_t)E_AT_N * 4);
    // per-edge rank buffers (atomicAdd returns from count3_k)
    int* rk_aa = (int*)alloc((size_t)E_AA_N * 4);
    int* rk_ta = (int*)alloc((size_t)E_TA_N * 4);
    int* rk_at = (int*)alloc((size_t)E_AT_N * 4);
    char* zbase = alloc(((size_t)(N_ASTN + 1) * 2 + (N_TESTN + 1)) * 4);
    int* cnt_aa = (int*)zbase;
    int* cnt_ta = cnt_aa + (N_ASTN + 1);
    int* cnt_at = cnt_ta + (N_ASTN + 1);
    size_t zbytes = ((size_t)(N_ASTN + 1) * 2 + (N_TESTN + 1)) * 4;
    int* bsumA = (int*)alloc(256 * 4);
    int* bsumT = (int*)alloc(256 * 4);
    int* bsumX = (int*)alloc(256 * 4);
    // aggAT (10000x128 bf16 = 2.56 MB) overlays the rank buffers (12 MB),
    // which are dead after fill3_k.
    __bf16* aggAT = (__bf16*)rk_aa;

    if (ws_size < off) {
        hipMemsetAsync(d_out, 0, (size_t)out_size * 2, stream);
        return;
    }

    detect_k<<<1, 256, 0, stream>>>((const unsigned short*)ast_content, flag);
    ConvSpec spec;
    spec.src[0] = d_in[9];  spec.off[0] = P_EMB;
    spec.src[1] = d_in[10]; spec.off[1] = P_CW;
    spec.src[2] = d_in[11]; spec.off[2] = P_CB;
    spec.src[3] = d_in[12]; spec.off[3] = P_TEMB;
    spec.src[4] = d_in[13]; spec.off[4] = P_WAA;
    spec.src[5] = d_in[14]; spec.off[5] = P_WAT;
    spec.src[6] = d_in[15]; spec.off[6] = P_WTA;
    spec.src[7] = d_in[16]; spec.off[7] = P_BAST;
    spec.src[8] = d_in[17]; spec.off[8] = P_BTEST;
    spec.src[9] = d_in[18]; spec.off[9] = P_DECW;
    spec.src[10] = d_in[19]; spec.off[10] = P_DECB;
    spec.total = P_TOTAL;
    conv_params_k<<<256, 256, 0, stream>>>(spec, flag, (unsigned short*)params);

    hipMemsetAsync(zbase, 0, zbytes, stream);

    count3_k<<<3072, 256, 0, stream>>>(dst_aa, dst_ta, dst_at, cnt_aa, cnt_ta, cnt_at,
                                       rk_aa, rk_ta, rk_at);
    scan_bsum3<<<2 * NBA + NBT, 256, 0, stream>>>(cnt_aa, cnt_ta, cnt_at, bsumA, bsumT, bsumX);
    scan_top3<<<3, 256, 0, stream>>>(bsumA, bsumT, bsumX);
    scan_final3<<<2 * NBA + NBT, 256, 0, stream>>>(cnt_aa, cnt_ta, cnt_at,
                                                   bsumA, bsumT, bsumX,
                                                   ip_aa, ip_ta, ip_at);
    fill3_k<<<3072, 256, 0, stream>>>(src_aa, dst_aa, rk_aa, ip_aa, e_aa,
                                      src_ta, dst_ta, rk_ta, ip_ta, e_ta,
                                      src_at, dst_at, rk_at, ip_at, e_at);

    encode_emb<<<N_ASTN * 32 / 256, 256, 0, stream>>>(ast_label, (const unsigned*)(params + P_EMB),
                                                      (unsigned*)hA);
    gemm_rowblk<4><<<1568, 256, 0, stream>>>(ast_content, params + P_CW, params + P_CB,
                                             hA + 64, N_ASTN, 256, 256, HDIM, flag);
    init_test<<<N_TESTN * 64 / 256, 256, 0, stream>>>((const unsigned*)(params + P_TEMB),
                                                      (unsigned*)hT);

    const uint4* decWq = (const uint4*)(params + P_DECW);
    const unsigned* decbU = (const unsigned*)(params + P_DECB);
    const int resflags[5] = {0, 1, 0, 1, 0};
    for (int l = 0; l < 5; l++) {
        const __bf16* Waa = params + P_WAA + (size_t)l * HDIM * HDIM;
        const __bf16* Wat = params + P_WAT + (size_t)l * HDIM * HDIM;
        const __bf16* Wta = params + P_WTA + (size_t)l * HDIM * HDIM;
        // TT = old hT @ Wta (must precede hT update)
        gemm_rowblk<8><<<160, 256, 0, stream>>>(hT, Wta, nullptr, TT, N_TESTN, HDIM, HDIM, HDIM, nullptr);
        // aggregate-then-transform for at-edges: mean(hA[src]) then tiny GEMM
        agg_at_k<<<N_TESTN / 16, 256, 0, stream>>>(
            (const uint4*)hA, ip_at, e_at, (uint4*)aggAT, N_TESTN);
        gemm_rowblk<8><<<1568, 256, 0, stream>>>(hA, Waa, nullptr, TA, N_ASTN, HDIM, HDIM, HDIM, nullptr);
        test_transform<<<256, 256, 0, stream>>>(
            aggAT, Wat, params + P_BTEST + (size_t)l * HDIM, hT, N_TESTN, resflags[l]);
        if (l < 4) {
            ast_update<0><<<N_ASTN / 16, 256, 0, stream>>>(
                (const uint4*)TA, (const uint4*)TT, ip_aa, e_aa, ip_ta, e_ta,
                (const uint4*)(params + P_BAST + (size_t)l * HDIM), (unsigned*)hA,
                N_ASTN, resflags[l], nullptr, nullptr, nullptr, nullptr);
        } else {
            // layer 4: fused decoder epilogue, hA write skipped
            ast_update<1><<<N_ASTN / 16, 256, 0, stream>>>(
                (const uint4*)TA, (const uint4*)TT, ip_aa, e_aa, ip_ta, e_ta,
                (const uint4*)(params + P_BAST + (size_t)l * HDIM), (unsigned*)hA,
                N_ASTN, 0, decWq, decbU, d_out, flag);
        }
    }
}